// Round 1
// baseline (5764.978 us; speedup 1.0000x reference)
//
#include <hip/hip_runtime.h>
#include <math.h>

#define N_NODES 50000
#define E_EDGES 600000
#define D_DIM 128
#define OUT_DIM 40
#define N_ITERS 5
#define GAMMA_C 0.1f
#define EPS_C 0.1f

// ---------------------------------------------------------------------------
// A = W_anti - W_anti^T - gamma*I   (stored row-major A[j][k], used as x@A.T)
// ---------------------------------------------------------------------------
__global__ __launch_bounds__(256) void prep_A_kernel(const float* __restrict__ Wanti,
                                                     float* __restrict__ A) {
    int i = blockIdx.x * 256 + threadIdx.x;          // 16384 elements
    int r = i >> 7, c = i & 127;
    float v = Wanti[r * 128 + c] - Wanti[c * 128 + r];
    if (r == c) v -= GAMMA_C;
    A[i] = v;
}

// ---------------------------------------------------------------------------
// C[i,j] = sum_k X[i,k] * W[j,k] (+ bias[j])     K = 128 (fully staged)
// Tile: 64 rows x 64 cols, 256 threads, 4x4 microtile / thread.
// LDS float4 columns XOR-swizzled by (row>>2)&7 so compute-phase b128 reads
// are <=2-way bank-aliased (free).
// ---------------------------------------------------------------------------
__global__ __launch_bounds__(256) void gemm_xwt(const float* __restrict__ X,
                                                const float* __restrict__ W,
                                                const float* __restrict__ bias,
                                                float* __restrict__ C, int M) {
    __shared__ float Xs[64 * 128];
    __shared__ float Ws[64 * 128];
    const int tid = threadIdx.x;
    const int rowBase = blockIdx.x * 64;
    const int colBase = blockIdx.y * 64;

    // stage X tile (64x128 floats) as float4, swizzled
#pragma unroll
    for (int p = 0; p < 8; ++p) {
        int fi = p * 256 + tid;            // float4 index in tile [0,2048)
        int r = fi >> 5, c4 = fi & 31;
        int gr = rowBase + r;
        float4 v = make_float4(0.f, 0.f, 0.f, 0.f);
        if (gr < M) v = *(const float4*)(X + (size_t)gr * 128 + c4 * 4);
        *(float4*)(Xs + r * 128 + ((c4 ^ ((r >> 2) & 7)) << 2)) = v;
    }
    // stage W tile (64x128) — W has 128 rows, colBase in {0,64}, no guard
#pragma unroll
    for (int p = 0; p < 8; ++p) {
        int fi = p * 256 + tid;
        int r = fi >> 5, c4 = fi & 31;
        float4 v = *(const float4*)(W + (size_t)(colBase + r) * 128 + c4 * 4);
        *(float4*)(Ws + r * 128 + ((c4 ^ ((r >> 2) & 7)) << 2)) = v;
    }
    __syncthreads();

    const int tx = tid & 15, ty = tid >> 4;
    const int r0 = ty * 4;                 // rows in tile
    const int c0 = tx * 4;                 // cols in tile
    const int swx = ty & 7;                // (r>>2)&7 for all 4 rows
    const int swy = tx & 7;                // (c>>2)&7 for all 4 cols

    float acc[4][4] = {};
#pragma unroll 8
    for (int k4 = 0; k4 < 32; ++k4) {
        const int cox = (k4 ^ swx) << 2;
        const int cow = (k4 ^ swy) << 2;
        float4 a[4], b[4];
#pragma unroll
        for (int i = 0; i < 4; ++i) a[i] = *(const float4*)(Xs + (r0 + i) * 128 + cox);
#pragma unroll
        for (int j = 0; j < 4; ++j) b[j] = *(const float4*)(Ws + (c0 + j) * 128 + cow);
#pragma unroll
        for (int i = 0; i < 4; ++i)
#pragma unroll
            for (int j = 0; j < 4; ++j) {
                acc[i][j] = fmaf(a[i].x, b[j].x, acc[i][j]);
                acc[i][j] = fmaf(a[i].y, b[j].y, acc[i][j]);
                acc[i][j] = fmaf(a[i].z, b[j].z, acc[i][j]);
                acc[i][j] = fmaf(a[i].w, b[j].w, acc[i][j]);
            }
    }

    float4 bv = make_float4(0.f, 0.f, 0.f, 0.f);
    if (bias) bv = *(const float4*)(bias + colBase + c0);
#pragma unroll
    for (int i = 0; i < 4; ++i) {
        int gr = rowBase + r0 + i;
        if (gr >= M) continue;
        float4 v = make_float4(acc[i][0] + bv.x, acc[i][1] + bv.y,
                               acc[i][2] + bv.z, acc[i][3] + bv.w);
        *(float4*)(C + (size_t)gr * 128 + colBase + c0) = v;
    }
}

// ---------------------------------------------------------------------------
// agg[dst[e]] += ew[e] * neigh[src[e]]   (32 threads / edge, float4 each)
// ---------------------------------------------------------------------------
__global__ __launch_bounds__(256) void scatter_kernel(const float* __restrict__ neigh,
                                                      const int* __restrict__ src,
                                                      const int* __restrict__ dst,
                                                      const float* __restrict__ ew,
                                                      float* __restrict__ agg) {
    int gid = blockIdx.x * 256 + threadIdx.x;
    int e = gid >> 5;
    if (e >= E_EDGES) return;
    int q = gid & 31;
    int s = src[e], d = dst[e];
    float w = ew[e];
    float4 v = *(const float4*)(neigh + (size_t)s * 128 + q * 4);
    float* o = agg + (size_t)d * 128 + q * 4;
    atomicAdd(o + 0, w * v.x);
    atomicAdd(o + 1, w * v.y);
    atomicAdd(o + 2, w * v.z);
    atomicAdd(o + 3, w * v.w);
}

// ---------------------------------------------------------------------------
// x += eps * tanh(conv)   (float4 grid-stride-free, exact size)
// ---------------------------------------------------------------------------
__global__ __launch_bounds__(256) void update_kernel(float* __restrict__ x,
                                                     const float* __restrict__ conv) {
    int i = blockIdx.x * 256 + threadIdx.x;   // over float4s: 1,600,000
    float4 xv = *(float4*)(x + i * 4);
    float4 cv = *(const float4*)(conv + i * 4);
    xv.x += EPS_C * tanhf(cv.x);
    xv.y += EPS_C * tanhf(cv.y);
    xv.z += EPS_C * tanhf(cv.z);
    xv.w += EPS_C * tanhf(cv.w);
    *(float4*)(x + i * 4) = xv;
}

// ---------------------------------------------------------------------------
// out[i,j] = sum_k x[i,k]*Wout[j,k] + bout[j]    N=40, K=128
// ---------------------------------------------------------------------------
__global__ __launch_bounds__(256) void out_kernel(const float* __restrict__ x,
                                                  const float* __restrict__ Wout,
                                                  const float* __restrict__ bout,
                                                  float* __restrict__ out, int M) {
    __shared__ float Ws[OUT_DIM * 128];   // 20 KB
    __shared__ float Xs[64 * 128];        // 32 KB
    const int tid = threadIdx.x;
    const int rowBase = blockIdx.x * 64;
#pragma unroll
    for (int p = 0; p < 5; ++p) {         // 40*128/4 = 1280 float4
        int fi = p * 256 + tid;
        *(float4*)(Ws + fi * 4) = *(const float4*)(Wout + fi * 4);
    }
#pragma unroll
    for (int p = 0; p < 8; ++p) {
        int fi = p * 256 + tid;
        int r = fi >> 5, c4 = fi & 31;
        int gr = rowBase + r;
        float4 v = make_float4(0.f, 0.f, 0.f, 0.f);
        if (gr < M) v = *(const float4*)(x + (size_t)gr * 128 + c4 * 4);
        *(float4*)(Xs + r * 128 + c4 * 4) = v;
    }
    __syncthreads();

    for (int idx = tid; idx < 64 * OUT_DIM; idx += 256) {
        int r = idx / OUT_DIM, c = idx - r * OUT_DIM;
        int gr = rowBase + r;
        if (gr >= M) continue;
        float acc = 0.f;
#pragma unroll
        for (int k = 0; k < 128; k += 4) {
            float4 a = *(const float4*)(Xs + r * 128 + k);
            float4 b = *(const float4*)(Ws + c * 128 + k);
            acc = fmaf(a.x, b.x, acc);
            acc = fmaf(a.y, b.y, acc);
            acc = fmaf(a.z, b.z, acc);
            acc = fmaf(a.w, b.w, acc);
        }
        out[(size_t)gr * OUT_DIM + c] = acc + bout[c];
    }
}

extern "C" void kernel_launch(void* const* d_in, const int* in_sizes, int n_in,
                              void* d_out, int out_size, void* d_ws, size_t ws_size,
                              hipStream_t stream) {
    const float* x_in   = (const float*)d_in[0];
    const int*   ei     = (const int*)  d_in[1];   // (2,E): src=ei, dst=ei+E
    const float* ew     = (const float*)d_in[2];
    const float* W_emb  = (const float*)d_in[3];
    const float* b_emb  = (const float*)d_in[4];
    const float* W_lin  = (const float*)d_in[5];
    const float* W_anti = (const float*)d_in[6];
    const float* b_conv = (const float*)d_in[7];
    const float* W_out  = (const float*)d_in[8];
    const float* b_out  = (const float*)d_in[9];
    float* out = (float*)d_out;

    // workspace layout (floats): x | neigh | agg | A   => 76.87 MB
    float* xbuf  = (float*)d_ws;
    float* neigh = xbuf  + (size_t)N_NODES * D_DIM;
    float* agg   = neigh + (size_t)N_NODES * D_DIM;
    float* Abuf  = agg   + (size_t)N_NODES * D_DIM;

    const dim3 gemmGrid(782, 2);   // ceil(50000/64) x (128/64)

    prep_A_kernel<<<64, 256, 0, stream>>>(W_anti, Abuf);
    // x = x @ W_emb.T + b_emb
    gemm_xwt<<<gemmGrid, 256, 0, stream>>>(x_in, W_emb, b_emb, xbuf, N_NODES);

    for (int it = 0; it < N_ITERS; ++it) {
        // neigh = x @ W_lin.T
        gemm_xwt<<<gemmGrid, 256, 0, stream>>>(xbuf, W_lin, nullptr, neigh, N_NODES);
        // agg = x @ A.T + b_conv   (scatter accumulates on top)
        gemm_xwt<<<gemmGrid, 256, 0, stream>>>(xbuf, Abuf, b_conv, agg, N_NODES);
        // agg[dst] += ew * neigh[src]
        scatter_kernel<<<75000, 256, 0, stream>>>(neigh, ei, ei + E_EDGES, ew, agg);
        // x += eps * tanh(agg)
        update_kernel<<<6250, 256, 0, stream>>>(xbuf, agg);
    }
    // out = x @ W_out.T + b_out
    out_kernel<<<782, 256, 0, stream>>>(xbuf, W_out, b_out, out, N_NODES);
}

// Round 2
// 1102.325 us; speedup vs baseline: 5.2298x; 5.2298x over previous
//
#include <hip/hip_runtime.h>
#include <math.h>

#define N_NODES 50000
#define E_EDGES 600000
#define D_DIM 128
#define OUT_DIM 40
#define N_ITERS 5
#define GAMMA_C 0.1f
#define EPS_C 0.1f

// ---------------------------------------------------------------------------
// A = W_anti - W_anti^T - gamma*I
// ---------------------------------------------------------------------------
__global__ __launch_bounds__(256) void prep_A_kernel(const float* __restrict__ Wanti,
                                                     float* __restrict__ A) {
    int i = blockIdx.x * 256 + threadIdx.x;          // 16384 elements
    int r = i >> 7, c = i & 127;
    float v = Wanti[r * 128 + c] - Wanti[c * 128 + r];
    if (r == c) v -= GAMMA_C;
    A[i] = v;
}

// ---------------------------------------------------------------------------
// GEMM: C[i,j] = sum_k X[i,k]*W[j,k] (+bias[j]); K=128 fully staged in LDS.
// 64x64 tile, 256 threads, 4x4 microtile. XOR-swizzled float4 columns keep
// compute-phase ds_read_b128 at <=2-way bank aliasing (free per m136).
// ---------------------------------------------------------------------------
__global__ __launch_bounds__(256) void gemm_xwt(const float* __restrict__ X,
                                                const float* __restrict__ W,
                                                const float* __restrict__ bias,
                                                float* __restrict__ C, int M) {
    __shared__ float Xs[64 * 128];
    __shared__ float Ws[64 * 128];
    const int tid = threadIdx.x;
    const int rowBase = blockIdx.x * 64;
    const int colBase = blockIdx.y * 64;

#pragma unroll
    for (int p = 0; p < 8; ++p) {
        int fi = p * 256 + tid;
        int r = fi >> 5, c4 = fi & 31;
        int gr = rowBase + r;
        float4 v = make_float4(0.f, 0.f, 0.f, 0.f);
        if (gr < M) v = *(const float4*)(X + (size_t)gr * 128 + c4 * 4);
        *(float4*)(Xs + r * 128 + ((c4 ^ ((r >> 2) & 7)) << 2)) = v;
    }
#pragma unroll
    for (int p = 0; p < 8; ++p) {
        int fi = p * 256 + tid;
        int r = fi >> 5, c4 = fi & 31;
        float4 v = *(const float4*)(W + (size_t)(colBase + r) * 128 + c4 * 4);
        *(float4*)(Ws + r * 128 + ((c4 ^ ((r >> 2) & 7)) << 2)) = v;
    }
    __syncthreads();

    const int tx = tid & 15, ty = tid >> 4;
    const int r0 = ty * 4, c0 = tx * 4;
    const int swx = ty & 7, swy = tx & 7;

    float acc[4][4] = {};
#pragma unroll 8
    for (int k4 = 0; k4 < 32; ++k4) {
        const int cox = (k4 ^ swx) << 2;
        const int cow = (k4 ^ swy) << 2;
        float4 a[4], b[4];
#pragma unroll
        for (int i = 0; i < 4; ++i) a[i] = *(const float4*)(Xs + (r0 + i) * 128 + cox);
#pragma unroll
        for (int j = 0; j < 4; ++j) b[j] = *(const float4*)(Ws + (c0 + j) * 128 + cow);
#pragma unroll
        for (int i = 0; i < 4; ++i)
#pragma unroll
            for (int j = 0; j < 4; ++j) {
                acc[i][j] = fmaf(a[i].x, b[j].x, acc[i][j]);
                acc[i][j] = fmaf(a[i].y, b[j].y, acc[i][j]);
                acc[i][j] = fmaf(a[i].z, b[j].z, acc[i][j]);
                acc[i][j] = fmaf(a[i].w, b[j].w, acc[i][j]);
            }
    }

    float4 bv = make_float4(0.f, 0.f, 0.f, 0.f);
    if (bias) bv = *(const float4*)(bias + colBase + c0);
#pragma unroll
    for (int i = 0; i < 4; ++i) {
        int gr = rowBase + r0 + i;
        if (gr >= M) continue;
        float4 v = make_float4(acc[i][0] + bv.x, acc[i][1] + bv.y,
                               acc[i][2] + bv.z, acc[i][3] + bv.w);
        *(float4*)(C + (size_t)gr * 128 + colBase + c0) = v;
    }
}

// ---------------------------------------------------------------------------
// CSR build (once per launch; edge structure is iteration-invariant)
// ---------------------------------------------------------------------------
__global__ __launch_bounds__(256) void zero_int_kernel(int* __restrict__ p, int n) {
    int i = blockIdx.x * 256 + threadIdx.x;
    if (i < n) p[i] = 0;
}

__global__ __launch_bounds__(256) void hist_kernel(const int* __restrict__ dst,
                                                   int* __restrict__ cnt) {
    int e = blockIdx.x * 256 + threadIdx.x;
    if (e < E_EDGES) atomicAdd(&cnt[dst[e]], 1);
}

// single-block exclusive scan of deg[N] -> rowStart[N]; also init cursor=rowStart.
// deg aliases cursor in memory: read deg[i] BEFORE writing cursor[i].
__global__ __launch_bounds__(1024) void scan_kernel(const int* __restrict__ deg,
                                                    int* __restrict__ rowStart,
                                                    int* __restrict__ cursor) {
    __shared__ int part[1024];
    const int t = threadIdx.x;
    const int CH = (N_NODES + 1023) / 1024;       // 49
    int beg = t * CH;
    int end = beg + CH; if (end > N_NODES) end = N_NODES;
    int s = 0;
    for (int i = beg; i < end; ++i) s += deg[i];
    part[t] = s;
    __syncthreads();
    for (int off = 1; off < 1024; off <<= 1) {
        int v = 0;
        if (t >= off) v = part[t - off];
        __syncthreads();
        if (t >= off) part[t] += v;
        __syncthreads();
    }
    int run = part[t] - s;                        // exclusive prefix of this chunk
    for (int i = beg; i < end; ++i) {
        int d = deg[i];                           // read before cursor write (alias!)
        rowStart[i] = run;
        cursor[i] = run;
        run += d;
    }
}

// scatter edges into CSR order: es[pos]=src, ewt[pos]=w
__global__ __launch_bounds__(256) void build_kernel(const int* __restrict__ src,
                                                    const int* __restrict__ dst,
                                                    const float* __restrict__ ew,
                                                    int* __restrict__ cursor,
                                                    int* __restrict__ es,
                                                    float* __restrict__ ewt) {
    int e = blockIdx.x * 256 + threadIdx.x;
    if (e >= E_EDGES) return;
    int d = dst[e];
    int pos = atomicAdd(&cursor[d], 1);
    es[pos] = src[e];
    ewt[pos] = ew[e];
}

// ---------------------------------------------------------------------------
// Fused aggregate + update: one 32-lane group per node (float4/lane over D).
//   conv = convIn[node] + sum_e w_e * neigh[src_e];  x[node] += eps*tanh(conv)
// No atomics: each node owned by exactly one half-wave.
// ---------------------------------------------------------------------------
__global__ __launch_bounds__(256) void aggregate_update_kernel(
        const float* __restrict__ neigh, const int* __restrict__ es,
        const float* __restrict__ ewt, const int* __restrict__ rowStart,
        const int* __restrict__ rowEnd,  // cursor after build == end offsets
        const float* __restrict__ convIn, float* __restrict__ x) {
    int gid = blockIdx.x * 256 + threadIdx.x;
    int node = gid >> 5;
    if (node >= N_NODES) return;
    int q = gid & 31;
    int e = rowStart[node], end = rowEnd[node];

    float4 sum = make_float4(0.f, 0.f, 0.f, 0.f);
    int s0 = 0; float w0 = 0.f;
    if (e < end) { s0 = es[e]; w0 = ewt[e]; }
    while (e < end) {
        int s = s0; float w = w0;
        ++e;
        if (e < end) { s0 = es[e]; w0 = ewt[e]; }   // prefetch next edge meta
        float4 v = *(const float4*)(neigh + (size_t)s * 128 + q * 4);
        sum.x = fmaf(w, v.x, sum.x);
        sum.y = fmaf(w, v.y, sum.y);
        sum.z = fmaf(w, v.z, sum.z);
        sum.w = fmaf(w, v.w, sum.w);
    }
    size_t off = (size_t)node * 128 + q * 4;
    float4 c = *(const float4*)(convIn + off);
    float4 xv = *(float4*)(x + off);
    xv.x += EPS_C * tanhf(c.x + sum.x);
    xv.y += EPS_C * tanhf(c.y + sum.y);
    xv.z += EPS_C * tanhf(c.z + sum.z);
    xv.w += EPS_C * tanhf(c.w + sum.w);
    *(float4*)(x + off) = xv;
}

// ---------------------------------------------------------------------------
// out[i,j] = sum_k x[i,k]*Wout[j,k] + bout[j]
// ---------------------------------------------------------------------------
__global__ __launch_bounds__(256) void out_kernel(const float* __restrict__ x,
                                                  const float* __restrict__ Wout,
                                                  const float* __restrict__ bout,
                                                  float* __restrict__ out, int M) {
    __shared__ float Ws[OUT_DIM * 128];
    __shared__ float Xs[64 * 128];
    const int tid = threadIdx.x;
    const int rowBase = blockIdx.x * 64;
#pragma unroll
    for (int p = 0; p < 5; ++p) {
        int fi = p * 256 + tid;
        *(float4*)(Ws + fi * 4) = *(const float4*)(Wout + fi * 4);
    }
#pragma unroll
    for (int p = 0; p < 8; ++p) {
        int fi = p * 256 + tid;
        int r = fi >> 5, c4 = fi & 31;
        int gr = rowBase + r;
        float4 v = make_float4(0.f, 0.f, 0.f, 0.f);
        if (gr < M) v = *(const float4*)(x + (size_t)gr * 128 + c4 * 4);
        *(float4*)(Xs + r * 128 + c4 * 4) = v;
    }
    __syncthreads();

    for (int idx = tid; idx < 64 * OUT_DIM; idx += 256) {
        int r = idx / OUT_DIM, c = idx - r * OUT_DIM;
        int gr = rowBase + r;
        if (gr >= M) continue;
        float acc = 0.f;
#pragma unroll
        for (int k = 0; k < 128; k += 4) {
            float4 a = *(const float4*)(Xs + r * 128 + k);
            float4 b = *(const float4*)(Ws + c * 128 + k);
            acc = fmaf(a.x, b.x, acc);
            acc = fmaf(a.y, b.y, acc);
            acc = fmaf(a.z, b.z, acc);
            acc = fmaf(a.w, b.w, acc);
        }
        out[(size_t)gr * OUT_DIM + c] = acc + bout[c];
    }
}

extern "C" void kernel_launch(void* const* d_in, const int* in_sizes, int n_in,
                              void* d_out, int out_size, void* d_ws, size_t ws_size,
                              hipStream_t stream) {
    const float* x_in   = (const float*)d_in[0];
    const int*   ei     = (const int*)  d_in[1];   // (2,E) as int32: src=ei, dst=ei+E
    const float* ew     = (const float*)d_in[2];
    const float* W_emb  = (const float*)d_in[3];
    const float* b_emb  = (const float*)d_in[4];
    const float* W_lin  = (const float*)d_in[5];
    const float* W_anti = (const float*)d_in[6];
    const float* b_conv = (const float*)d_in[7];
    const float* W_out  = (const float*)d_in[8];
    const float* b_out  = (const float*)d_in[9];
    float* out = (float*)d_out;

    // workspace layout: x | neigh | agg | A | rowStart | cursor | es | ewt  (~82 MB)
    float* xbuf  = (float*)d_ws;
    float* neigh = xbuf  + (size_t)N_NODES * D_DIM;
    float* agg   = neigh + (size_t)N_NODES * D_DIM;
    float* Abuf  = agg   + (size_t)N_NODES * D_DIM;
    int*   rowStart = (int*)(Abuf + D_DIM * D_DIM);
    int*   cursor   = rowStart + N_NODES;
    int*   es       = cursor + N_NODES;
    float* ewt      = (float*)(es + E_EDGES);

    const int* src = ei;
    const int* dst = ei + E_EDGES;
    const dim3 gemmGrid(782, 2);
    const int edgeBlocks = (E_EDGES + 255) / 256;          // 2344

    // ---- CSR build (once) ----
    zero_int_kernel<<<(N_NODES + 255) / 256, 256, 0, stream>>>(cursor, N_NODES);
    hist_kernel<<<edgeBlocks, 256, 0, stream>>>(dst, cursor);
    scan_kernel<<<1, 1024, 0, stream>>>(cursor, rowStart, cursor);
    build_kernel<<<edgeBlocks, 256, 0, stream>>>(src, dst, ew, cursor, es, ewt);
    // after build: cursor[d] == row end offset

    prep_A_kernel<<<64, 256, 0, stream>>>(W_anti, Abuf);
    gemm_xwt<<<gemmGrid, 256, 0, stream>>>(x_in, W_emb, b_emb, xbuf, N_NODES);

    for (int it = 0; it < N_ITERS; ++it) {
        gemm_xwt<<<gemmGrid, 256, 0, stream>>>(xbuf, W_lin, nullptr, neigh, N_NODES);
        gemm_xwt<<<gemmGrid, 256, 0, stream>>>(xbuf, Abuf, b_conv, agg, N_NODES);
        aggregate_update_kernel<<<(N_NODES * 32 + 255) / 256, 256, 0, stream>>>(
            neigh, es, ewt, rowStart, cursor, agg, xbuf);
    }
    out_kernel<<<782, 256, 0, stream>>>(xbuf, W_out, b_out, out, N_NODES);
}

// Round 3
// 598.217 us; speedup vs baseline: 9.6369x; 1.8427x over previous
//
#include <hip/hip_runtime.h>
#include <math.h>

#define N_NODES 50000
#define E_EDGES 600000
#define D_DIM 128
#define OUT_DIM 40
#define N_ITERS 5
#define GAMMA_C 0.1f
#define EPS_C 0.1f

typedef short v8s __attribute__((ext_vector_type(8)));   // 8 bf16 (4 VGPRs)
typedef float v4f __attribute__((ext_vector_type(4)));   // MFMA accumulator
typedef unsigned int uint;
typedef unsigned short ushort;

__device__ __forceinline__ ushort f2bf(float f) {        // RNE fp32->bf16
    union { float f; uint u; } v; v.f = f;
    uint u = v.u;
    uint r = 0x7fffu + ((u >> 16) & 1u);
    return (ushort)((u + r) >> 16);
}
__device__ __forceinline__ float bf2f(ushort h) {
    union { uint u; float f; } v; v.u = ((uint)h) << 16;
    return v.f;
}

// ---------------------------------------------------------------------------
// Weight prep (once): W_emb -> bf16; Wcat = [W_lin ; A] -> bf16,
// A = W_anti - W_anti^T - gamma*I
// ---------------------------------------------------------------------------
__global__ __launch_bounds__(256) void prep_w_kernel(const float* __restrict__ Wemb,
                                                     const float* __restrict__ Wlin,
                                                     const float* __restrict__ Wanti,
                                                     ushort* __restrict__ WembH,
                                                     ushort* __restrict__ WcatH) {
    int i = blockIdx.x * 256 + threadIdx.x;              // 16384
    int r = i >> 7, c = i & 127;
    WembH[i] = f2bf(Wemb[i]);
    WcatH[i] = f2bf(Wlin[i]);
    float a = Wanti[r * 128 + c] - Wanti[c * 128 + r];
    if (r == c) a -= GAMMA_C;
    WcatH[16384 + i] = f2bf(a);
}

// ---------------------------------------------------------------------------
// MFMA bf16 GEMM core helpers. Tile 128x128, 256 thr (4 waves), K=128 staged.
// LDS layout: 16-chunk (8 bf16) rows, chunk XOR-swizzled by (row&7) ->
// compute-phase ds_read_b128 spreads 8 lanes per 4-bank group (optimal).
// Fragment layouts per verified m89/m120 mapping:
//   A[m=lane&15][k=quad*8+j], B[n=lane&15][k=quad*8+j],
//   C/D: col=lane&15, row=quad*4+reg.
// ---------------------------------------------------------------------------

// iteration GEMM: y=0: neighH = bf16(xh @ W_lin^T); y=1: agg = xh @ A^T + b_conv
__global__ __launch_bounds__(256) void mfma_iter_gemm(const ushort* __restrict__ Xh,
                                                      const ushort* __restrict__ Wcat,
                                                      const float* __restrict__ bconv,
                                                      ushort* __restrict__ neighH,
                                                      float* __restrict__ aggF,
                                                      int M) {
    __shared__ ushort Xs[128 * 128];
    __shared__ ushort Ws[128 * 128];
    const int tid = threadIdx.x;
    const int rowBase = blockIdx.x * 128;
    const int isAgg = blockIdx.y;
    const ushort* W = Wcat + (size_t)isAgg * (128 * 128);

#pragma unroll
    for (int p = 0; p < 8; ++p) {
        int cid = p * 256 + tid;                 // 2048 chunks of 8 bf16
        int r = cid >> 4, c8 = cid & 15;
        int gr = rowBase + r;
        uint4 xv = make_uint4(0, 0, 0, 0);
        if (gr < M) xv = *(const uint4*)(Xh + (size_t)gr * 128 + c8 * 8);
        *(uint4*)(Xs + r * 128 + ((c8 ^ (r & 7)) << 3)) = xv;
        uint4 wv = *(const uint4*)(W + (size_t)r * 128 + c8 * 8);
        *(uint4*)(Ws + r * 128 + ((c8 ^ (r & 7)) << 3)) = wv;
    }
    __syncthreads();

    const int lane = tid & 63;
    const int wv = tid >> 6;
    const int wrow = (wv & 1) * 64;
    const int wcol = (wv >> 1) * 64;
    const int l16 = lane & 15;
    const int q = lane >> 4;

    v4f acc[4][4];
#pragma unroll
    for (int i = 0; i < 4; ++i)
#pragma unroll
        for (int j = 0; j < 4; ++j) {
            v4f z = {0.f, 0.f, 0.f, 0.f};
            acc[i][j] = z;
        }

#pragma unroll
    for (int ks = 0; ks < 4; ++ks) {
        const int chunk = ks * 4 + q;
        v8s a[4], b[4];
#pragma unroll
        for (int i = 0; i < 4; ++i) {
            int m = wrow + i * 16 + l16;
            a[i] = *(const v8s*)(Xs + m * 128 + ((chunk ^ (m & 7)) << 3));
        }
#pragma unroll
        for (int j = 0; j < 4; ++j) {
            int n = wcol + j * 16 + l16;
            b[j] = *(const v8s*)(Ws + n * 128 + ((chunk ^ (n & 7)) << 3));
        }
#pragma unroll
        for (int i = 0; i < 4; ++i)
#pragma unroll
            for (int j = 0; j < 4; ++j)
                acc[i][j] = __builtin_amdgcn_mfma_f32_16x16x32_bf16(a[i], b[j], acc[i][j], 0, 0, 0);
    }

    if (!isAgg) {
#pragma unroll
        for (int j = 0; j < 4; ++j) {
            int col = wcol + j * 16 + l16;
#pragma unroll
            for (int i = 0; i < 4; ++i) {
                int grB = rowBase + wrow + i * 16 + q * 4;
#pragma unroll
                for (int r = 0; r < 4; ++r) {
                    int gr = grB + r;
                    if (gr < M) neighH[(size_t)gr * 128 + col] = f2bf(acc[i][j][r]);
                }
            }
        }
    } else {
#pragma unroll
        for (int j = 0; j < 4; ++j) {
            int col = wcol + j * 16 + l16;
            float bj = bconv[col];
#pragma unroll
            for (int i = 0; i < 4; ++i) {
                int grB = rowBase + wrow + i * 16 + q * 4;
#pragma unroll
                for (int r = 0; r < 4; ++r) {
                    int gr = grB + r;
                    if (gr < M) aggF[(size_t)gr * 128 + col] = acc[i][j][r] + bj;
                }
            }
        }
    }
}

// embed GEMM: x = x0 @ W_emb^T + b_emb  (fp32 in, writes fp32 x AND bf16 xh)
__global__ __launch_bounds__(256) void mfma_embed_gemm(const float* __restrict__ Xf,
                                                       const ushort* __restrict__ Wh,
                                                       const float* __restrict__ bias,
                                                       float* __restrict__ xF,
                                                       ushort* __restrict__ xH,
                                                       int M) {
    __shared__ ushort Xs[128 * 128];
    __shared__ ushort Ws[128 * 128];
    const int tid = threadIdx.x;
    const int rowBase = blockIdx.x * 128;

#pragma unroll
    for (int p = 0; p < 8; ++p) {
        int cid = p * 256 + tid;
        int r = cid >> 4, c8 = cid & 15;
        int gr = rowBase + r;
        uint4 val = make_uint4(0, 0, 0, 0);
        if (gr < M) {
            const float* ptr = Xf + (size_t)gr * 128 + c8 * 8;
            float4 f0 = *(const float4*)ptr;
            float4 f1 = *(const float4*)(ptr + 4);
            val.x = (uint)f2bf(f0.x) | ((uint)f2bf(f0.y) << 16);
            val.y = (uint)f2bf(f0.z) | ((uint)f2bf(f0.w) << 16);
            val.z = (uint)f2bf(f1.x) | ((uint)f2bf(f1.y) << 16);
            val.w = (uint)f2bf(f1.z) | ((uint)f2bf(f1.w) << 16);
        }
        *(uint4*)(Xs + r * 128 + ((c8 ^ (r & 7)) << 3)) = val;
        uint4 wv = *(const uint4*)(Wh + (size_t)r * 128 + c8 * 8);
        *(uint4*)(Ws + r * 128 + ((c8 ^ (r & 7)) << 3)) = wv;
    }
    __syncthreads();

    const int lane = tid & 63;
    const int wv = tid >> 6;
    const int wrow = (wv & 1) * 64;
    const int wcol = (wv >> 1) * 64;
    const int l16 = lane & 15;
    const int q = lane >> 4;

    v4f acc[4][4];
#pragma unroll
    for (int i = 0; i < 4; ++i)
#pragma unroll
        for (int j = 0; j < 4; ++j) {
            v4f z = {0.f, 0.f, 0.f, 0.f};
            acc[i][j] = z;
        }

#pragma unroll
    for (int ks = 0; ks < 4; ++ks) {
        const int chunk = ks * 4 + q;
        v8s a[4], b[4];
#pragma unroll
        for (int i = 0; i < 4; ++i) {
            int m = wrow + i * 16 + l16;
            a[i] = *(const v8s*)(Xs + m * 128 + ((chunk ^ (m & 7)) << 3));
        }
#pragma unroll
        for (int j = 0; j < 4; ++j) {
            int n = wcol + j * 16 + l16;
            b[j] = *(const v8s*)(Ws + n * 128 + ((chunk ^ (n & 7)) << 3));
        }
#pragma unroll
        for (int i = 0; i < 4; ++i)
#pragma unroll
            for (int j = 0; j < 4; ++j)
                acc[i][j] = __builtin_amdgcn_mfma_f32_16x16x32_bf16(a[i], b[j], acc[i][j], 0, 0, 0);
    }

#pragma unroll
    for (int j = 0; j < 4; ++j) {
        int col = wcol + j * 16 + l16;
        float bj = bias[col];
#pragma unroll
        for (int i = 0; i < 4; ++i) {
            int grB = rowBase + wrow + i * 16 + q * 4;
#pragma unroll
            for (int r = 0; r < 4; ++r) {
                int gr = grB + r;
                if (gr < M) {
                    float v = acc[i][j][r] + bj;
                    xF[(size_t)gr * 128 + col] = v;
                    xH[(size_t)gr * 128 + col] = f2bf(v);
                }
            }
        }
    }
}

// ---------------------------------------------------------------------------
// CSR build (once per launch; edge structure is iteration-invariant)
// ---------------------------------------------------------------------------
__global__ __launch_bounds__(256) void zero_int_kernel(int* __restrict__ p, int n) {
    int i = blockIdx.x * 256 + threadIdx.x;
    if (i < n) p[i] = 0;
}

__global__ __launch_bounds__(256) void hist_kernel(const int* __restrict__ dst,
                                                   int* __restrict__ cnt) {
    int e = blockIdx.x * 256 + threadIdx.x;
    if (e < E_EDGES) atomicAdd(&cnt[dst[e]], 1);
}

__global__ __launch_bounds__(1024) void scan_kernel(const int* __restrict__ deg,
                                                    int* __restrict__ rowStart,
                                                    int* __restrict__ cursor) {
    __shared__ int part[1024];
    const int t = threadIdx.x;
    const int CH = (N_NODES + 1023) / 1024;
    int beg = t * CH;
    int end = beg + CH; if (end > N_NODES) end = N_NODES;
    int s = 0;
    for (int i = beg; i < end; ++i) s += deg[i];
    part[t] = s;
    __syncthreads();
    for (int off = 1; off < 1024; off <<= 1) {
        int v = 0;
        if (t >= off) v = part[t - off];
        __syncthreads();
        if (t >= off) part[t] += v;
        __syncthreads();
    }
    int run = part[t] - s;
    for (int i = beg; i < end; ++i) {
        int d = deg[i];                          // read before cursor write (alias!)
        rowStart[i] = run;
        cursor[i] = run;
        run += d;
    }
}

__global__ __launch_bounds__(256) void build_kernel(const int* __restrict__ src,
                                                    const int* __restrict__ dst,
                                                    const float* __restrict__ ew,
                                                    int* __restrict__ cursor,
                                                    int* __restrict__ es,
                                                    float* __restrict__ ewt) {
    int e = blockIdx.x * 256 + threadIdx.x;
    if (e >= E_EDGES) return;
    int d = dst[e];
    int pos = atomicAdd(&cursor[d], 1);
    es[pos] = src[e];
    ewt[pos] = ew[e];
}

// ---------------------------------------------------------------------------
// Fused aggregate + update: one 32-lane group per node, 4 floats per lane.
// Gather reads bf16 rows (halved traffic). Writes fp32 x and bf16 xh.
// ---------------------------------------------------------------------------
__global__ __launch_bounds__(256) void aggregate_update_kernel(
        const ushort* __restrict__ neighH, const int* __restrict__ es,
        const float* __restrict__ ewt, const int* __restrict__ rowStart,
        const int* __restrict__ rowEnd, const float* __restrict__ convIn,
        float* __restrict__ x, ushort* __restrict__ xh) {
    int gid = blockIdx.x * 256 + threadIdx.x;
    int node = gid >> 5;
    if (node >= N_NODES) return;
    int q = gid & 31;
    int e = rowStart[node], end = rowEnd[node];

    float4 sum = make_float4(0.f, 0.f, 0.f, 0.f);
    int s0 = 0; float w0 = 0.f;
    if (e < end) { s0 = es[e]; w0 = ewt[e]; }
    while (e < end) {
        int s = s0; float w = w0;
        ++e;
        if (e < end) { s0 = es[e]; w0 = ewt[e]; }     // prefetch next edge meta
        ushort4 v = *(const ushort4*)(neighH + (size_t)s * 128 + q * 4);
        sum.x = fmaf(w, bf2f(v.x), sum.x);
        sum.y = fmaf(w, bf2f(v.y), sum.y);
        sum.z = fmaf(w, bf2f(v.z), sum.z);
        sum.w = fmaf(w, bf2f(v.w), sum.w);
    }
    size_t off = (size_t)node * 128 + q * 4;
    float4 c = *(const float4*)(convIn + off);
    float4 xv = *(float4*)(x + off);
    xv.x += EPS_C * tanhf(c.x + sum.x);
    xv.y += EPS_C * tanhf(c.y + sum.y);
    xv.z += EPS_C * tanhf(c.z + sum.z);
    xv.w += EPS_C * tanhf(c.w + sum.w);
    *(float4*)(x + off) = xv;
    ushort4 h;
    h.x = f2bf(xv.x); h.y = f2bf(xv.y); h.z = f2bf(xv.z); h.w = f2bf(xv.w);
    *(ushort4*)(xh + off) = h;
}

// ---------------------------------------------------------------------------
// Readout: out = x @ W_out^T + b_out (fp32, 64x64 guarded tile, swizzled LDS
// -> replaces the conflict-ridden out_kernel: 6.2e7 conflicts -> ~0)
// ---------------------------------------------------------------------------
__global__ __launch_bounds__(256) void out_gemm(const float* __restrict__ X,
                                                const float* __restrict__ W,
                                                const float* __restrict__ bias,
                                                float* __restrict__ C, int M) {
    __shared__ float Xs[64 * 128];
    __shared__ float Ws[64 * 128];
    const int tid = threadIdx.x;
    const int rowBase = blockIdx.x * 64;

#pragma unroll
    for (int p = 0; p < 8; ++p) {
        int fi = p * 256 + tid;
        int r = fi >> 5, c4 = fi & 31;
        int gr = rowBase + r;
        float4 v = make_float4(0.f, 0.f, 0.f, 0.f);
        if (gr < M) v = *(const float4*)(X + (size_t)gr * 128 + c4 * 4);
        *(float4*)(Xs + r * 128 + ((c4 ^ ((r >> 2) & 7)) << 2)) = v;
    }
#pragma unroll
    for (int p = 0; p < 8; ++p) {
        int fi = p * 256 + tid;
        int r = fi >> 5, c4 = fi & 31;
        float4 v = make_float4(0.f, 0.f, 0.f, 0.f);
        if (r < OUT_DIM) v = *(const float4*)(W + (size_t)r * 128 + c4 * 4);
        *(float4*)(Ws + r * 128 + ((c4 ^ ((r >> 2) & 7)) << 2)) = v;
    }
    __syncthreads();

    const int tx = tid & 15, ty = tid >> 4;
    const int r0 = ty * 4, c0 = tx * 4;
    const int swx = ty & 7, swy = tx & 7;

    float acc[4][4] = {};
#pragma unroll 8
    for (int k4 = 0; k4 < 32; ++k4) {
        const int cox = (k4 ^ swx) << 2;
        const int cow = (k4 ^ swy) << 2;
        float4 a[4], b[4];
#pragma unroll
        for (int i = 0; i < 4; ++i) a[i] = *(const float4*)(Xs + (r0 + i) * 128 + cox);
#pragma unroll
        for (int j = 0; j < 4; ++j) b[j] = *(const float4*)(Ws + (c0 + j) * 128 + cow);
#pragma unroll
        for (int i = 0; i < 4; ++i)
#pragma unroll
            for (int j = 0; j < 4; ++j) {
                acc[i][j] = fmaf(a[i].x, b[j].x, acc[i][j]);
                acc[i][j] = fmaf(a[i].y, b[j].y, acc[i][j]);
                acc[i][j] = fmaf(a[i].z, b[j].z, acc[i][j]);
                acc[i][j] = fmaf(a[i].w, b[j].w, acc[i][j]);
            }
    }

    if (c0 < OUT_DIM) {
        float4 bv = *(const float4*)(bias + c0);
#pragma unroll
        for (int i = 0; i < 4; ++i) {
            int gr = rowBase + r0 + i;
            if (gr >= M) continue;
            float4 v = make_float4(acc[i][0] + bv.x, acc[i][1] + bv.y,
                                   acc[i][2] + bv.z, acc[i][3] + bv.w);
            *(float4*)(C + (size_t)gr * OUT_DIM + c0) = v;
        }
    }
}

extern "C" void kernel_launch(void* const* d_in, const int* in_sizes, int n_in,
                              void* d_out, int out_size, void* d_ws, size_t ws_size,
                              hipStream_t stream) {
    const float* x_in   = (const float*)d_in[0];
    const int*   ei     = (const int*)  d_in[1];   // (2,E) int32: src=ei, dst=ei+E
    const float* ew     = (const float*)d_in[2];
    const float* W_emb  = (const float*)d_in[3];
    const float* b_emb  = (const float*)d_in[4];
    const float* W_lin  = (const float*)d_in[5];
    const float* W_anti = (const float*)d_in[6];
    const float* b_conv = (const float*)d_in[7];
    const float* W_out  = (const float*)d_in[8];
    const float* b_out  = (const float*)d_in[9];
    float* out = (float*)d_out;

    // workspace: x(f32) | agg(f32) | xh(bf16) | neighH(bf16) | WembH | WcatH |
    //            rowStart | cursor | es | ewt        (~82 MB)
    float*  xbuf   = (float*)d_ws;
    float*  agg    = xbuf + (size_t)N_NODES * D_DIM;
    ushort* xh     = (ushort*)(agg + (size_t)N_NODES * D_DIM);
    ushort* neighH = xh + (size_t)N_NODES * D_DIM;
    ushort* WembH  = neighH + (size_t)N_NODES * D_DIM;
    ushort* WcatH  = WembH + D_DIM * D_DIM;
    int*    rowStart = (int*)(WcatH + 2 * D_DIM * D_DIM);
    int*    cursor   = rowStart + N_NODES;
    int*    es       = cursor + N_NODES;
    float*  ewt      = (float*)(es + E_EDGES);

    const int* src = ei;
    const int* dst = ei + E_EDGES;
    const int edgeBlocks = (E_EDGES + 255) / 256;
    const int gemmBlocksX = (N_NODES + 127) / 128;       // 391

    // ---- CSR build (once) ----
    zero_int_kernel<<<(N_NODES + 255) / 256, 256, 0, stream>>>(cursor, N_NODES);
    hist_kernel<<<edgeBlocks, 256, 0, stream>>>(dst, cursor);
    scan_kernel<<<1, 1024, 0, stream>>>(cursor, rowStart, cursor);
    build_kernel<<<edgeBlocks, 256, 0, stream>>>(src, dst, ew, cursor, es, ewt);

    // ---- weights to bf16 ----
    prep_w_kernel<<<64, 256, 0, stream>>>(W_emb, W_lin, W_anti, WembH, WcatH);

    // ---- embed ----
    mfma_embed_gemm<<<gemmBlocksX, 256, 0, stream>>>(x_in, WembH, b_emb, xbuf, xh, N_NODES);

    for (int it = 0; it < N_ITERS; ++it) {
        mfma_iter_gemm<<<dim3(gemmBlocksX, 2), 256, 0, stream>>>(
            xh, WcatH, b_conv, neighH, agg, N_NODES);
        aggregate_update_kernel<<<(N_NODES * 32 + 255) / 256, 256, 0, stream>>>(
            neighH, es, ewt, rowStart, cursor, agg, xbuf, xh);
    }
    out_gemm<<<(N_NODES + 63) / 64, 256, 0, stream>>>(xbuf, W_out, b_out, out, N_NODES);
}

// Round 4
// 493.200 us; speedup vs baseline: 11.6889x; 1.2129x over previous
//
#include <hip/hip_runtime.h>
#include <math.h>

#define N_NODES 50000
#define E_EDGES 600000
#define D_DIM 128
#define OUT_DIM 40
#define N_ITERS 5
#define GAMMA_C 0.1f
#define EPS_C 0.1f
#define SCAN_BLOCKS 196          // 196*256 = 50176 >= N_NODES

typedef short v8s __attribute__((ext_vector_type(8)));   // 8 bf16 (4 VGPRs)
typedef float v4f __attribute__((ext_vector_type(4)));   // MFMA accumulator
typedef unsigned int uint;
typedef unsigned short ushort;

__device__ __forceinline__ ushort f2bf(float f) {        // RNE fp32->bf16
    union { float f; uint u; } v; v.f = f;
    uint u = v.u;
    uint r = 0x7fffu + ((u >> 16) & 1u);
    return (ushort)((u + r) >> 16);
}
__device__ __forceinline__ float bf2f(ushort h) {
    union { uint u; float f; } v; v.u = ((uint)h) << 16;
    return v.f;
}

// ---------------------------------------------------------------------------
// Weight prep (once): W_emb -> bf16; Wcat = [W_lin ; A] -> bf16,
// A = W_anti - W_anti^T - gamma*I
// ---------------------------------------------------------------------------
__global__ __launch_bounds__(256) void prep_w_kernel(const float* __restrict__ Wemb,
                                                     const float* __restrict__ Wlin,
                                                     const float* __restrict__ Wanti,
                                                     ushort* __restrict__ WembH,
                                                     ushort* __restrict__ WcatH) {
    int i = blockIdx.x * 256 + threadIdx.x;              // 16384
    int r = i >> 7, c = i & 127;
    WembH[i] = f2bf(Wemb[i]);
    WcatH[i] = f2bf(Wlin[i]);
    float a = Wanti[r * 128 + c] - Wanti[c * 128 + r];
    if (r == c) a -= GAMMA_C;
    WcatH[16384 + i] = f2bf(a);
}

// ---------------------------------------------------------------------------
// MFMA bf16 GEMM. Tile 128x128, 256 thr (4 waves), K=128 fully staged.
// LDS: 8-bf16 chunks XOR-swizzled by (row&7) -> conflict-free ds_read_b128.
// Fragment layouts (verified m89/m120): A[m=lane&15][k=quad*8+j],
// B[n=lane&15][k=quad*8+j], C/D: col=lane&15, row=quad*4+reg.
// ---------------------------------------------------------------------------

// iteration GEMM: y=0: neighH = bf16(xh @ W_lin^T); y=1: agg = xh @ A^T + b_conv
__global__ __launch_bounds__(256) void mfma_iter_gemm(const ushort* __restrict__ Xh,
                                                      const ushort* __restrict__ Wcat,
                                                      const float* __restrict__ bconv,
                                                      ushort* __restrict__ neighH,
                                                      float* __restrict__ aggF,
                                                      int M) {
    __shared__ ushort Xs[128 * 128];
    __shared__ ushort Ws[128 * 128];
    const int tid = threadIdx.x;
    const int rowBase = blockIdx.x * 128;
    const int isAgg = blockIdx.y;
    const ushort* W = Wcat + (size_t)isAgg * (128 * 128);

#pragma unroll
    for (int p = 0; p < 8; ++p) {
        int cid = p * 256 + tid;                 // 2048 chunks of 8 bf16
        int r = cid >> 4, c8 = cid & 15;
        int gr = rowBase + r;
        uint4 xv = make_uint4(0, 0, 0, 0);
        if (gr < M) xv = *(const uint4*)(Xh + (size_t)gr * 128 + c8 * 8);
        *(uint4*)(Xs + r * 128 + ((c8 ^ (r & 7)) << 3)) = xv;
        uint4 wv = *(const uint4*)(W + (size_t)r * 128 + c8 * 8);
        *(uint4*)(Ws + r * 128 + ((c8 ^ (r & 7)) << 3)) = wv;
    }
    __syncthreads();

    const int lane = tid & 63;
    const int wv = tid >> 6;
    const int wrow = (wv & 1) * 64;
    const int wcol = (wv >> 1) * 64;
    const int l16 = lane & 15;
    const int q = lane >> 4;

    v4f acc[4][4];
#pragma unroll
    for (int i = 0; i < 4; ++i)
#pragma unroll
        for (int j = 0; j < 4; ++j) {
            v4f z = {0.f, 0.f, 0.f, 0.f};
            acc[i][j] = z;
        }

#pragma unroll
    for (int ks = 0; ks < 4; ++ks) {
        const int chunk = ks * 4 + q;
        v8s a[4], b[4];
#pragma unroll
        for (int i = 0; i < 4; ++i) {
            int m = wrow + i * 16 + l16;
            a[i] = *(const v8s*)(Xs + m * 128 + ((chunk ^ (m & 7)) << 3));
        }
#pragma unroll
        for (int j = 0; j < 4; ++j) {
            int n = wcol + j * 16 + l16;
            b[j] = *(const v8s*)(Ws + n * 128 + ((chunk ^ (n & 7)) << 3));
        }
#pragma unroll
        for (int i = 0; i < 4; ++i)
#pragma unroll
            for (int j = 0; j < 4; ++j)
                acc[i][j] = __builtin_amdgcn_mfma_f32_16x16x32_bf16(a[i], b[j], acc[i][j], 0, 0, 0);
    }

    if (!isAgg) {
#pragma unroll
        for (int j = 0; j < 4; ++j) {
            int col = wcol + j * 16 + l16;
#pragma unroll
            for (int i = 0; i < 4; ++i) {
                int grB = rowBase + wrow + i * 16 + q * 4;
#pragma unroll
                for (int r = 0; r < 4; ++r) {
                    int gr = grB + r;
                    if (gr < M) neighH[(size_t)gr * 128 + col] = f2bf(acc[i][j][r]);
                }
            }
        }
    } else {
#pragma unroll
        for (int j = 0; j < 4; ++j) {
            int col = wcol + j * 16 + l16;
            float bj = bconv[col];
#pragma unroll
            for (int i = 0; i < 4; ++i) {
                int grB = rowBase + wrow + i * 16 + q * 4;
#pragma unroll
                for (int r = 0; r < 4; ++r) {
                    int gr = grB + r;
                    if (gr < M) aggF[(size_t)gr * 128 + col] = acc[i][j][r] + bj;
                }
            }
        }
    }
}

// embed GEMM: x = x0 @ W_emb^T + b_emb  (fp32 in, writes fp32 x AND bf16 xh)
__global__ __launch_bounds__(256) void mfma_embed_gemm(const float* __restrict__ Xf,
                                                       const ushort* __restrict__ Wh,
                                                       const float* __restrict__ bias,
                                                       float* __restrict__ xF,
                                                       ushort* __restrict__ xH,
                                                       int M) {
    __shared__ ushort Xs[128 * 128];
    __shared__ ushort Ws[128 * 128];
    const int tid = threadIdx.x;
    const int rowBase = blockIdx.x * 128;

#pragma unroll
    for (int p = 0; p < 8; ++p) {
        int cid = p * 256 + tid;
        int r = cid >> 4, c8 = cid & 15;
        int gr = rowBase + r;
        uint4 val = make_uint4(0, 0, 0, 0);
        if (gr < M) {
            const float* ptr = Xf + (size_t)gr * 128 + c8 * 8;
            float4 f0 = *(const float4*)ptr;
            float4 f1 = *(const float4*)(ptr + 4);
            val.x = (uint)f2bf(f0.x) | ((uint)f2bf(f0.y) << 16);
            val.y = (uint)f2bf(f0.z) | ((uint)f2bf(f0.w) << 16);
            val.z = (uint)f2bf(f1.x) | ((uint)f2bf(f1.y) << 16);
            val.w = (uint)f2bf(f1.z) | ((uint)f2bf(f1.w) << 16);
        }
        *(uint4*)(Xs + r * 128 + ((c8 ^ (r & 7)) << 3)) = val;
        uint4 wv = *(const uint4*)(Wh + (size_t)r * 128 + c8 * 8);
        *(uint4*)(Ws + r * 128 + ((c8 ^ (r & 7)) << 3)) = wv;
    }
    __syncthreads();

    const int lane = tid & 63;
    const int wv = tid >> 6;
    const int wrow = (wv & 1) * 64;
    const int wcol = (wv >> 1) * 64;
    const int l16 = lane & 15;
    const int q = lane >> 4;

    v4f acc[4][4];
#pragma unroll
    for (int i = 0; i < 4; ++i)
#pragma unroll
        for (int j = 0; j < 4; ++j) {
            v4f z = {0.f, 0.f, 0.f, 0.f};
            acc[i][j] = z;
        }

#pragma unroll
    for (int ks = 0; ks < 4; ++ks) {
        const int chunk = ks * 4 + q;
        v8s a[4], b[4];
#pragma unroll
        for (int i = 0; i < 4; ++i) {
            int m = wrow + i * 16 + l16;
            a[i] = *(const v8s*)(Xs + m * 128 + ((chunk ^ (m & 7)) << 3));
        }
#pragma unroll
        for (int j = 0; j < 4; ++j) {
            int n = wcol + j * 16 + l16;
            b[j] = *(const v8s*)(Ws + n * 128 + ((chunk ^ (n & 7)) << 3));
        }
#pragma unroll
        for (int i = 0; i < 4; ++i)
#pragma unroll
            for (int j = 0; j < 4; ++j)
                acc[i][j] = __builtin_amdgcn_mfma_f32_16x16x32_bf16(a[i], b[j], acc[i][j], 0, 0, 0);
    }

#pragma unroll
    for (int j = 0; j < 4; ++j) {
        int col = wcol + j * 16 + l16;
        float bj = bias[col];
#pragma unroll
        for (int i = 0; i < 4; ++i) {
            int grB = rowBase + wrow + i * 16 + q * 4;
#pragma unroll
            for (int r = 0; r < 4; ++r) {
                int gr = grB + r;
                if (gr < M) {
                    float v = acc[i][j][r] + bj;
                    xF[(size_t)gr * 128 + col] = v;
                    xH[(size_t)gr * 128 + col] = f2bf(v);
                }
            }
        }
    }
}

// ---------------------------------------------------------------------------
// CSR build (once per launch). Multi-block 3-phase scan replaces the 110 µs
// single-block scan (0.14% occupancy, pure latency stall).
// ---------------------------------------------------------------------------
__global__ __launch_bounds__(256) void zero_int_kernel(int* __restrict__ p, int n) {
    int i = blockIdx.x * 256 + threadIdx.x;
    if (i < n) p[i] = 0;
}

__global__ __launch_bounds__(256) void hist_kernel(const int* __restrict__ dst,
                                                   int* __restrict__ cnt) {
    int e = blockIdx.x * 256 + threadIdx.x;
    if (e < E_EDGES) atomicAdd(&cnt[dst[e]], 1);
}

// phase 1: per-block exclusive scan of deg -> rowStart (block-local), block sums
__global__ __launch_bounds__(256) void scan_phase1(const int* __restrict__ deg,
                                                   int* __restrict__ localEx,
                                                   int* __restrict__ blockSums) {
    __shared__ int tmp[256];
    const int t = threadIdx.x;
    const int i = blockIdx.x * 256 + t;
    int v = (i < N_NODES) ? deg[i] : 0;
    tmp[t] = v;
    __syncthreads();
#pragma unroll
    for (int off = 1; off < 256; off <<= 1) {
        int u = (t >= off) ? tmp[t - off] : 0;
        __syncthreads();
        tmp[t] += u;
        __syncthreads();
    }
    if (i < N_NODES) localEx[i] = tmp[t] - v;        // exclusive within block
    if (t == 255) blockSums[blockIdx.x] = tmp[255];
}

// phase 2: single block scans the 196 block sums -> exclusive block offsets
__global__ __launch_bounds__(256) void scan_phase2(int* __restrict__ blockSums) {
    __shared__ int tmp[256];
    const int t = threadIdx.x;
    int v = (t < SCAN_BLOCKS) ? blockSums[t] : 0;
    tmp[t] = v;
    __syncthreads();
#pragma unroll
    for (int off = 1; off < 256; off <<= 1) {
        int u = (t >= off) ? tmp[t - off] : 0;
        __syncthreads();
        tmp[t] += u;
        __syncthreads();
    }
    if (t < SCAN_BLOCKS) blockSums[t] = tmp[t] - v;  // exclusive
}

// phase 3: add block offset; init cursor = rowStart (overwrites deg buffer)
__global__ __launch_bounds__(256) void scan_phase3(int* __restrict__ rowStart,
                                                   const int* __restrict__ blockSums,
                                                   int* __restrict__ cursor) {
    const int i = blockIdx.x * 256 + threadIdx.x;
    if (i >= N_NODES) return;
    int v = rowStart[i] + blockSums[blockIdx.x];
    rowStart[i] = v;
    cursor[i] = v;
}

// scatter edges into CSR order: es[pos]=src, ewt[pos]=w
__global__ __launch_bounds__(256) void build_kernel(const int* __restrict__ src,
                                                    const int* __restrict__ dst,
                                                    const float* __restrict__ ew,
                                                    int* __restrict__ cursor,
                                                    int* __restrict__ es,
                                                    float* __restrict__ ewt) {
    int e = blockIdx.x * 256 + threadIdx.x;
    if (e >= E_EDGES) return;
    int d = dst[e];
    int pos = atomicAdd(&cursor[d], 1);
    es[pos] = src[e];
    ewt[pos] = ew[e];
}

// ---------------------------------------------------------------------------
// Fused aggregate + update: one 32-lane group per node, 4 floats per lane.
// Unroll-4 edge loop: 4 independent gathers in flight (latency hiding).
// ---------------------------------------------------------------------------
__global__ __launch_bounds__(256) void aggregate_update_kernel(
        const ushort* __restrict__ neighH, const int* __restrict__ es,
        const float* __restrict__ ewt, const int* __restrict__ rowStart,
        const int* __restrict__ rowEnd, const float* __restrict__ convIn,
        float* __restrict__ x, ushort* __restrict__ xh) {
    int gid = blockIdx.x * 256 + threadIdx.x;
    int node = gid >> 5;
    if (node >= N_NODES) return;
    int q = gid & 31;
    int e = rowStart[node], end = rowEnd[node];

    float4 s0 = make_float4(0.f, 0.f, 0.f, 0.f);
    float4 s1 = make_float4(0.f, 0.f, 0.f, 0.f);
    float4 s2 = make_float4(0.f, 0.f, 0.f, 0.f);
    float4 s3 = make_float4(0.f, 0.f, 0.f, 0.f);
    for (; e + 4 <= end; e += 4) {
        int a0 = es[e], a1 = es[e + 1], a2 = es[e + 2], a3 = es[e + 3];
        float w0 = ewt[e], w1 = ewt[e + 1], w2 = ewt[e + 2], w3 = ewt[e + 3];
        ushort4 v0 = *(const ushort4*)(neighH + (size_t)a0 * 128 + q * 4);
        ushort4 v1 = *(const ushort4*)(neighH + (size_t)a1 * 128 + q * 4);
        ushort4 v2 = *(const ushort4*)(neighH + (size_t)a2 * 128 + q * 4);
        ushort4 v3 = *(const ushort4*)(neighH + (size_t)a3 * 128 + q * 4);
        s0.x = fmaf(w0, bf2f(v0.x), s0.x); s0.y = fmaf(w0, bf2f(v0.y), s0.y);
        s0.z = fmaf(w0, bf2f(v0.z), s0.z); s0.w = fmaf(w0, bf2f(v0.w), s0.w);
        s1.x = fmaf(w1, bf2f(v1.x), s1.x); s1.y = fmaf(w1, bf2f(v1.y), s1.y);
        s1.z = fmaf(w1, bf2f(v1.z), s1.z); s1.w = fmaf(w1, bf2f(v1.w), s1.w);
        s2.x = fmaf(w2, bf2f(v2.x), s2.x); s2.y = fmaf(w2, bf2f(v2.y), s2.y);
        s2.z = fmaf(w2, bf2f(v2.z), s2.z); s2.w = fmaf(w2, bf2f(v2.w), s2.w);
        s3.x = fmaf(w3, bf2f(v3.x), s3.x); s3.y = fmaf(w3, bf2f(v3.y), s3.y);
        s3.z = fmaf(w3, bf2f(v3.z), s3.z); s3.w = fmaf(w3, bf2f(v3.w), s3.w);
    }
    for (; e < end; ++e) {
        int a = es[e];
        float w = ewt[e];
        ushort4 v = *(const ushort4*)(neighH + (size_t)a * 128 + q * 4);
        s0.x = fmaf(w, bf2f(v.x), s0.x); s0.y = fmaf(w, bf2f(v.y), s0.y);
        s0.z = fmaf(w, bf2f(v.z), s0.z); s0.w = fmaf(w, bf2f(v.w), s0.w);
    }
    float4 sum = make_float4(s0.x + s1.x + s2.x + s3.x,
                             s0.y + s1.y + s2.y + s3.y,
                             s0.z + s1.z + s2.z + s3.z,
                             s0.w + s1.w + s2.w + s3.w);

    size_t off = (size_t)node * 128 + q * 4;
    float4 c = *(const float4*)(convIn + off);
    float4 xv = *(float4*)(x + off);
    xv.x += EPS_C * tanhf(c.x + sum.x);
    xv.y += EPS_C * tanhf(c.y + sum.y);
    xv.z += EPS_C * tanhf(c.z + sum.z);
    xv.w += EPS_C * tanhf(c.w + sum.w);
    *(float4*)(x + off) = xv;
    ushort4 h;
    h.x = f2bf(xv.x); h.y = f2bf(xv.y); h.z = f2bf(xv.z); h.w = f2bf(xv.w);
    *(ushort4*)(xh + off) = h;
}

// ---------------------------------------------------------------------------
// Readout: out = x @ W_out^T + b_out (fp32, swizzled LDS, conflict-free)
// ---------------------------------------------------------------------------
__global__ __launch_bounds__(256) void out_gemm(const float* __restrict__ X,
                                                const float* __restrict__ W,
                                                const float* __restrict__ bias,
                                                float* __restrict__ C, int M) {
    __shared__ float Xs[64 * 128];
    __shared__ float Ws[64 * 128];
    const int tid = threadIdx.x;
    const int rowBase = blockIdx.x * 64;

#pragma unroll
    for (int p = 0; p < 8; ++p) {
        int fi = p * 256 + tid;
        int r = fi >> 5, c4 = fi & 31;
        int gr = rowBase + r;
        float4 v = make_float4(0.f, 0.f, 0.f, 0.f);
        if (gr < M) v = *(const float4*)(X + (size_t)gr * 128 + c4 * 4);
        *(float4*)(Xs + r * 128 + ((c4 ^ ((r >> 2) & 7)) << 2)) = v;
    }
#pragma unroll
    for (int p = 0; p < 8; ++p) {
        int fi = p * 256 + tid;
        int r = fi >> 5, c4 = fi & 31;
        float4 v = make_float4(0.f, 0.f, 0.f, 0.f);
        if (r < OUT_DIM) v = *(const float4*)(W + (size_t)r * 128 + c4 * 4);
        *(float4*)(Ws + r * 128 + ((c4 ^ ((r >> 2) & 7)) << 2)) = v;
    }
    __syncthreads();

    const int tx = tid & 15, ty = tid >> 4;
    const int r0 = ty * 4, c0 = tx * 4;
    const int swx = ty & 7, swy = tx & 7;

    float acc[4][4] = {};
#pragma unroll 8
    for (int k4 = 0; k4 < 32; ++k4) {
        const int cox = (k4 ^ swx) << 2;
        const int cow = (k4 ^ swy) << 2;
        float4 a[4], b[4];
#pragma unroll
        for (int i = 0; i < 4; ++i) a[i] = *(const float4*)(Xs + (r0 + i) * 128 + cox);
#pragma unroll
        for (int j = 0; j < 4; ++j) b[j] = *(const float4*)(Ws + (c0 + j) * 128 + cow);
#pragma unroll
        for (int i = 0; i < 4; ++i)
#pragma unroll
            for (int j = 0; j < 4; ++j) {
                acc[i][j] = fmaf(a[i].x, b[j].x, acc[i][j]);
                acc[i][j] = fmaf(a[i].y, b[j].y, acc[i][j]);
                acc[i][j] = fmaf(a[i].z, b[j].z, acc[i][j]);
                acc[i][j] = fmaf(a[i].w, b[j].w, acc[i][j]);
            }
    }

    if (c0 < OUT_DIM) {
        float4 bv = *(const float4*)(bias + c0);
#pragma unroll
        for (int i = 0; i < 4; ++i) {
            int gr = rowBase + r0 + i;
            if (gr >= M) continue;
            float4 v = make_float4(acc[i][0] + bv.x, acc[i][1] + bv.y,
                                   acc[i][2] + bv.z, acc[i][3] + bv.w);
            *(float4*)(C + (size_t)gr * OUT_DIM + c0) = v;
        }
    }
}

extern "C" void kernel_launch(void* const* d_in, const int* in_sizes, int n_in,
                              void* d_out, int out_size, void* d_ws, size_t ws_size,
                              hipStream_t stream) {
    const float* x_in   = (const float*)d_in[0];
    const int*   ei     = (const int*)  d_in[1];   // (2,E) int32: src=ei, dst=ei+E
    const float* ew     = (const float*)d_in[2];
    const float* W_emb  = (const float*)d_in[3];
    const float* b_emb  = (const float*)d_in[4];
    const float* W_lin  = (const float*)d_in[5];
    const float* W_anti = (const float*)d_in[6];
    const float* b_conv = (const float*)d_in[7];
    const float* W_out  = (const float*)d_in[8];
    const float* b_out  = (const float*)d_in[9];
    float* out = (float*)d_out;

    // workspace: x(f32) | agg(f32) | xh(bf16) | neighH(bf16) | WembH | WcatH |
    //            rowStart | cursor | es | ewt | blockSums     (~82 MB)
    float*  xbuf   = (float*)d_ws;
    float*  agg    = xbuf + (size_t)N_NODES * D_DIM;
    ushort* xh     = (ushort*)(agg + (size_t)N_NODES * D_DIM);
    ushort* neighH = xh + (size_t)N_NODES * D_DIM;
    ushort* WembH  = neighH + (size_t)N_NODES * D_DIM;
    ushort* WcatH  = WembH + D_DIM * D_DIM;
    int*    rowStart = (int*)(WcatH + 2 * D_DIM * D_DIM);
    int*    cursor   = rowStart + N_NODES;
    int*    es       = cursor + N_NODES;
    float*  ewt      = (float*)(es + E_EDGES);
    int*    blockSums = (int*)(ewt + E_EDGES);

    const int* src = ei;
    const int* dst = ei + E_EDGES;
    const int edgeBlocks = (E_EDGES + 255) / 256;
    const int gemmBlocksX = (N_NODES + 127) / 128;       // 391

    // ---- CSR build (once; structure is iteration-invariant) ----
    zero_int_kernel<<<SCAN_BLOCKS, 256, 0, stream>>>(cursor, N_NODES);
    hist_kernel<<<edgeBlocks, 256, 0, stream>>>(dst, cursor);
    scan_phase1<<<SCAN_BLOCKS, 256, 0, stream>>>(cursor, rowStart, blockSums);
    scan_phase2<<<1, 256, 0, stream>>>(blockSums);
    scan_phase3<<<SCAN_BLOCKS, 256, 0, stream>>>(rowStart, blockSums, cursor);
    build_kernel<<<edgeBlocks, 256, 0, stream>>>(src, dst, ew, cursor, es, ewt);
    // after build: cursor[d] == row end offset

    // ---- weights to bf16 ----
    prep_w_kernel<<<64, 256, 0, stream>>>(W_emb, W_lin, W_anti, WembH, WcatH);

    // ---- embed ----
    mfma_embed_gemm<<<gemmBlocksX, 256, 0, stream>>>(x_in, WembH, b_emb, xbuf, xh, N_NODES);

    for (int it = 0; it < N_ITERS; ++it) {
        mfma_iter_gemm<<<dim3(gemmBlocksX, 2), 256, 0, stream>>>(
            xh, WcatH, b_conv, neighH, agg, N_NODES);
        aggregate_update_kernel<<<(N_NODES * 32 + 255) / 256, 256, 0, stream>>>(
            neighH, es, ewt, rowStart, cursor, agg, xbuf, xh);
    }
    out_gemm<<<(N_NODES + 63) / 64, 256, 0, stream>>>(xbuf, W_out, b_out, out, N_NODES);
}